// Round 17
// baseline (74.105 us; speedup 1.0000x reference)
//
#include <hip/hip_runtime.h>

#define BB 65536
#define TT 20
#define NG16 4096             // 16-element groups
#define FR_ROW 160            // u32 per (g,t): 16 elems x 10 u32 (5 hf + 5 hb pairs)

#define WS_AF  0              // 9 A-frag tiles x 64 lanes x 4 u32 = 2304
#define WS_OLD 2304           // fallback 14-frag region (3584 u32)
#define WS_FR  8192           // [g][t][FR_ROW] u32 = 52.4 MB
#define PKB 0x00003C00u       // f16 pair {1.0, 0.0}

#define LOG2E  1.442695041f
#define LOG2E2 2.885390082f

typedef unsigned u32;
typedef __fp16 f16x8 __attribute__((ext_vector_type(8)));
typedef float   f32x16 __attribute__((ext_vector_type(16)));
typedef float   f32x4v __attribute__((ext_vector_type(4)));
typedef u32     u32x4 __attribute__((ext_vector_type(4)));
typedef __fp16  h2v   __attribute__((ext_vector_type(2)));

__device__ __forceinline__ u32 pk_h16(float a, float b) {
    h2v v = __builtin_amdgcn_cvt_pkrtz(a, b);
    return __builtin_bit_cast(u32, v);
}
__device__ __forceinline__ f32x4v MFMA16(u32x4 a, u32x4 b, f32x4v c) {
    return __builtin_amdgcn_mfma_f32_16x16x32_f16(
        __builtin_bit_cast(f16x8, a), __builtin_bit_cast(f16x8, b), c, 0, 0, 0);
}
__device__ __forceinline__ f32x16 MFMA32(u32x4 a, u32x4 b, f32x16 c) {
    return __builtin_amdgcn_mfma_f32_32x32x16_f16(
        __builtin_bit_cast(f16x8, a), __builtin_bit_cast(f16x8, b), c, 0, 0, 0);
}

// Combined-rcp LSTM unit (8 trans ops/unit). Gate order i,f,g,o.
__device__ __forceinline__ void unit_cr(float ai, float af, float ag, float ao,
                                        float* c, float* h) {
    float pi = __builtin_amdgcn_exp2f(-LOG2E * ai);
    float pf = __builtin_amdgcn_exp2f(-LOG2E * af);
    float q  = __builtin_amdgcn_exp2f(LOG2E2 * ag);
    float fv = __builtin_amdgcn_rcpf(1.0f + pf);
    float ig = (q - 1.0f) * __builtin_amdgcn_rcpf((1.0f + pi) * (q + 1.0f));
    float cv = fmaf(fv, *c, ig);
    *c = cv;
    float po = __builtin_amdgcn_exp2f(-LOG2E * ao);
    float qc = __builtin_amdgcn_exp2f(LOG2E2 * cv);
    *h = (qc - 1.0f) * __builtin_amdgcn_rcpf((1.0f + po) * (qc + 1.0f));
}

// =================== prep (16x16x32 A-frags, blocked-16 map) ===================
// k-map (r15/r16-verified): lane quarter qq holds k in {4qq..4qq+3} U
// {16+4qq..16+4qq+3}; u32 j: k = (j>>1)*16 + 4qq + (j&1)*2 + s.
// Row perm: T=0 -> unit 2mq, T=1 -> unit 2mq+1, T=2 -> unit 8+mq (mq<2).
// => lane quarter q owns units {2q, 2q+1, 8+q}; h-exchange is u32 pair-slots.
// K-maps: fwd/bwd: x@k0-5, bias@k6, h@k8-17.  cb: hf@k0-9, hb@k10-19,
// h1@k20-29, bias@k30.
__global__ __launch_bounds__(256)
void prep16(
    const float* __restrict__ wih0, const float* __restrict__ whh0,
    const float* __restrict__ bih0, const float* __restrict__ bhh0,
    const float* __restrict__ wih0r,const float* __restrict__ whh0r,
    const float* __restrict__ bih0r,const float* __restrict__ bhh0r,
    const float* __restrict__ wih1r,const float* __restrict__ whh1r,
    const float* __restrict__ bih1r,const float* __restrict__ bhh1r,
    u32* __restrict__ ws)
{
    for (int gid = threadIdx.x; gid < 9 * 64 * 4; gid += 256) {
        int fid = gid >> 8;            // 0..8 = ct*3 + T
        int ct = fid / 3, T = fid % 3;
        int l = (gid >> 2) & 63, j = gid & 3;
        int m = l & 15, qq = l >> 4;
        int mq = m >> 2, gate = m & 3;
        int unit;
        if (T == 0)      unit = 2 * mq;
        else if (T == 1) unit = 2 * mq + 1;
        else             unit = (mq < 2) ? (8 + mq) : 99;
        float v[2] = {0.f, 0.f};
        if (unit <= 9) {
            int orow = gate * 10 + unit;
#pragma unroll
            for (int s = 0; s < 2; ++s) {
                int k = (j >> 1) * 16 + 4 * qq + (j & 1) * 2 + s;
                float val = 0.f;
                if (ct < 2) {
                    const float* wih = ct ? wih0r : wih0;
                    const float* whh = ct ? whh0r : whh0;
                    if (k < 6)            val = wih[orow * 6 + k];
                    else if (k == 6)      val = ct ? (bih0r[orow] + bhh0r[orow])
                                               : (bih0[orow] + bhh0[orow]);
                    else if (k >= 8 && k <= 17) val = whh[orow * 10 + (k - 8)];
                } else {
                    if (k < 20)           val = wih1r[orow * 20 + k];
                    else if (k <= 29)     val = whh1r[orow * 10 + (k - 20)];
                    else if (k == 30)     val = bih1r[orow] + bhh1r[orow];
                }
                v[s] = val;
            }
        }
        ws[WS_AF + (fid * 64 + l) * 4 + j] = pk_h16(v[0], v[1]);
    }
}

// ============ main: 4 waves / 2 groups; fwd & bwd in SEPARATE waves ============
// Phase A at 8 waves/SIMD (each wave = one layer-0 chain); phase B on waves 0,1.
struct Lds8 {
    u32   bx[2][TT][16][4];    // 10240 B  {x01, x23, x45, PKB}
    float m[2][TT][16];        //  2560 B  mask
    u32   hx[2][2][16][6];     //  1536 B  [group][fwd/bwd] h pair-slots
    u32   zpad[2];             //     8 B
};  // 14344 B -> 8 blocks/CU (32 waves/CU)

__global__ __launch_bounds__(256, 8)
void bilstm8(
    const int*   __restrict__ eidx, const float* __restrict__ f,
    const float* __restrict__ emb,  const float* __restrict__ fw,
    const float* __restrict__ fb,
    const u32* __restrict__ wsr, u32* __restrict__ fr,
    float* __restrict__ out)
{
    __shared__ Lds8 lds;
    const int tid  = threadIdx.x;
    const int lane = tid & 63;
    const int e    = lane & 15;
    const int q    = lane >> 4;
    const int wu   = __builtin_amdgcn_readfirstlane(tid >> 6);
    const int role = wu >> 1;                  // 0 = fwd, 1 = bwd
    const int gl   = wu & 1;                   // group-in-block
    const int g    = blockIdx.x * 2 + gl;
    const int xaddr16 = (e + 16) << 2;         // bpermute: quarter-1 lane, same e

    // ---- cooperative staging: both groups ----
    {
        float fw0=fw[0],fw1=fw[1],fw2=fw[2],fw3=fw[3],fw4=fw[4];
        float fw5=fw[5],fw6=fw[6],fw7=fw[7],fw8=fw[8];
        float fb0=fb[0],fb1=fb[1],fb2=fb[2];
#pragma unroll 1
        for (int it = 0; it < 3; ++it) {
            int idx = tid + it * 256;          // 0..639
            if (idx < 640) {
                int gg = idx / 320, rem = idx - gg * 320;
                int ee = rem / TT, t = rem - ee * TT;
                int gi = ((blockIdx.x * 2 + gg) * 16 + ee) * TT + t;
                float f0 = f[gi * 3], f1 = f[gi * 3 + 1], f2v = f[gi * 3 + 2];
                int ei = eidx[gi] * 3;
                float x0 = emb[ei], x1 = emb[ei + 1], x2 = emb[ei + 2];
                float x3 = fmaf(fw0, f0, fmaf(fw1, f1, fmaf(fw2, f2v, fb0)));
                float x4 = fmaf(fw3, f0, fmaf(fw4, f1, fmaf(fw5, f2v, fb1)));
                float x5 = fmaf(fw6, f0, fmaf(fw7, f1, fmaf(fw8, f2v, fb2)));
                lds.bx[gg][t][ee][0] = pk_h16(x0, x1);
                lds.bx[gg][t][ee][1] = pk_h16(x2, x3);
                lds.bx[gg][t][ee][2] = pk_h16(x4, x5);
                lds.bx[gg][t][ee][3] = PKB;
                lds.m[gg][t][ee]     = (f1 != 0.f) ? 1.f : 0.f;
            }
        }
        u32* zz = &lds.hx[0][0][0][0];         // zero all 4 h buffers (384 u32)
        zz[tid & 255] = 0u;
        if (tid < 128) zz[256 + tid] = 0u;
        if (tid < 2) lds.zpad[tid] = 0u;
    }
    __syncthreads();

    const u32* zp = lds.zpad;
    const u32x4* wv4 = (const u32x4*)(wsr + WS_AF);
    const f32x4v z4 = {};
    u32* frp = fr + (size_t)g * TT * FR_ROW;

    // ---- Phase A: one layer-0 chain per wave (fwd or bwd by role) ----
    // B-frag (blocked-16): q0:{x01,x23 | h89,0} q1:{x45,PKB | 0,0}
    //                      q2:{h01,h23 | 0,0}   q3:{h45,h67 | 0,0}
    {
        const int wb = role * 3;
        u32x4 W0 = wv4[(wb + 0) * 64 + lane];
        u32x4 W1 = wv4[(wb + 1) * 64 + lane];
        u32x4 W2 = wv4[(wb + 2) * 64 + lane];
        u32* hxO = &lds.hx[gl][role][e][0];
        const int t0   = role ? TT - 1 : 0;
        const int sdir = role ? -1 : 1;
        const u32* aX  = (q < 2) ? &lds.bx[gl][t0][e][2 * q] : &hxO[2 * (q - 2)];
        const u32* a2  = (q == 0) ? &hxO[4] : zp;
        const int  strA = (q < 2) ? sdir * 64 : 0;     // u32 stride per step
        u32* pMain = frp + t0 * FR_ROW + e * 10 + role * 5 + q;
        u32* pXtra = frp + t0 * FR_ROW + e * 10 + role * 5 + 4;
        const int strF = sdir * FR_ROW;

        float cS[3] = {0,0,0};
#pragma unroll 1
        for (int s = 0; s < TT; ++s) {
            u32x4 b; b[0] = aX[0]; b[1] = aX[1]; b[2] = *a2; b[3] = 0u;
            f32x4v A0 = MFMA16(W0, b, z4), A1 = MFMA16(W1, b, z4), A2 = MFMA16(W2, b, z4);
            float h0, h1, h2;
            unit_cr(A0[0], A0[1], A0[2], A0[3], &cS[0], &h0);
            unit_cr(A1[0], A1[1], A1[2], A1[3], &cS[1], &h1);
            unit_cr(A2[0], A2[1], A2[2], A2[3], &cS[2], &h2);
            u32 pP = pk_h16(h0, h1);
            hxO[q] = pP;
            u32 r9 = (u32)__builtin_amdgcn_ds_bpermute(xaddr16, (int)__float_as_uint(h2));
            u32 s4 = pk_h16(h2, __uint_as_float(r9));
            if (q == 0) hxO[4] = s4;
            *pMain = pP;
            if (q == 0) *pXtra = s4;
            aX += strA; pMain += strF; pXtra += strF;
        }
    }
    __syncthreads();   // drains vmem: fr pairs visible; phase A h-buffers done

    // ---- Phase B: layer-1 backward (waves 0,1; one group each) ----
    // q0:{hf01,hf23 | hb67,hb89}  q1:{hf45,hf67 | h1_01,h1_23}
    // q2:{hf89,hb01 | h1_45,h1_67}  q3:{hb23,hb45 | h1_89,PKB}
    if (wu < 2) {
        const int gB = blockIdx.x * 2 + wu;
        const int b0 = gB * 16;
        u32* frB = fr + (size_t)gB * TT * FR_ROW;
        u32x4 H0 = wv4[6 * 64 + lane], H1 = wv4[7 * 64 + lane], H2 = wv4[8 * 64 + lane];
        u32* hx1 = &lds.hx[wu][0][e][0];       // reuse group's fwd buffer as h1
        // re-zero h1 buffer (96 u32)
        u32* hz = &lds.hx[wu][0][0][0];
        hz[lane] = 0u;
        if (lane < 32) hz[64 + lane] = 0u;
        const u32* caddr = (q == 0) ? zp : &lds.hx[wu][0][e][2 * (q - 1)];
        const int loffA = e * 10 + q * 2;
        const int loffB = e * 10 + 8;
        float cH[3] = {0,0,0}, tot = 0.f;
        u32 La0 = frB[(TT - 1) * FR_ROW + loffA], La1 = frB[(TT - 1) * FR_ROW + loffA + 1];
        u32 Lb0 = frB[(TT - 1) * FR_ROW + loffB], Lb1 = frB[(TT - 1) * FR_ROW + loffB + 1];
#pragma unroll 1
        for (int t = TT - 1; t >= 0; --t) {
            u32 c0 = caddr[0], c1 = caddr[1];
            u32x4 bc;
            bc[0] = La0;
            bc[1] = La1;
            bc[2] = (q == 0) ? Lb0 : c0;
            bc[3] = (q == 0) ? Lb1 : ((q == 3) ? PKB : c1);
            if (t > 0) {                       // prefetch t-1
                La0 = frB[(t - 1) * FR_ROW + loffA]; La1 = frB[(t - 1) * FR_ROW + loffA + 1];
                Lb0 = frB[(t - 1) * FR_ROW + loffB]; Lb1 = frB[(t - 1) * FR_ROW + loffB + 1];
            }
            f32x4v D0 = MFMA16(H0, bc, z4), D1 = MFMA16(H1, bc, z4), D2 = MFMA16(H2, bc, z4);
            float h0, h1, h2;
            unit_cr(D0[0], D0[1], D0[2], D0[3], &cH[0], &h0);
            unit_cr(D1[0], D1[1], D1[2], D1[3], &cH[1], &h1);
            unit_cr(D2[0], D2[1], D2[2], D2[3], &cH[2], &h2);
            hx1[q] = pk_h16(h0, h1);
            u32 rH = (u32)__builtin_amdgcn_ds_bpermute(xaddr16, (int)__float_as_uint(h2));
            if (q == 0) hx1[4] = pk_h16(h2, __uint_as_float(rH));
            if (q == 1) {                      // unit 9 = 8+q at q=1 -> h2
                float ip = fmaxf(h2 * lds.m[wu][t][e], 0.f);
                out[BB + (b0 + e) * TT + t] = ip;
                tot += ip;
            }
        }
        if (q == 1) out[b0 + e] = tot;
    }
}

// =================== fallback (small ws): verified 32x32 r11 path ===================
__device__ __forceinline__ u32x4 pack_h32(const float* h, bool hi, int xaddr, u32 b3) {
    u32 send = hi ? pk_h16(h[3], h[4]) : __float_as_uint(h[4]);
    u32 recv = (u32)__builtin_amdgcn_ds_bpermute(xaddr, (int)send);
    u32 lo0 = pk_h16(h[0], h[1]), lo1 = pk_h16(h[2], h[3]);
    u32 hi0 = pk_h16(__uint_as_float(recv), h[0]);
    u32 hi1 = pk_h16(h[1], h[2]);
    u32x4 b;
    b[0] = hi ? hi0 : lo0; b[1] = hi ? hi1 : lo1;
    b[2] = hi ? 0u : recv; b[3] = b3;
    return b;
}
__device__ __forceinline__ void cell_update5(const f32x16 a0, const f32x16 a1,
                                             float* c, float* h) {
#pragma unroll
    for (int v = 0; v < 4; ++v)
        unit_cr(a0[v], a0[4 + v], a0[8 + v], a0[12 + v], &c[v], &h[v]);
    unit_cr(a1[0], a1[1], a1[2], a1[3], &c[4], &h[4]);
}
__device__ __forceinline__ int inv_pi(int row) {
    if (row < 32) { int q = row >> 3, rem = row & 7; return q * 10 + 5 * (rem >> 2) + (rem & 3); }
    if (row < 40) { int lo = row - 32; return (lo & 3) * 10 + 5 * (lo >> 2) + 4; }
    return -1;
}
__global__ __launch_bounds__(256)
void prep_old(
    const float* __restrict__ wih0, const float* __restrict__ whh0,
    const float* __restrict__ bih0, const float* __restrict__ bhh0,
    const float* __restrict__ wih0r,const float* __restrict__ whh0r,
    const float* __restrict__ bih0r,const float* __restrict__ bhh0r,
    const float* __restrict__ wih1r,const float* __restrict__ whh1r,
    const float* __restrict__ bih1r,const float* __restrict__ bhh1r,
    u32* __restrict__ ws)
{
    for (int gid = threadIdx.x; gid < 14 * 64 * 4; gid += 256) {
        int fid = gid >> 8, l = (gid >> 2) & 63, j = gid & 3;
        int gq = l >> 5;
        int tile, chunk;
        if (fid < 8) { tile = (fid >> 1) & 1; chunk = fid & 1; }
        else         { int q2 = fid - 8; tile = q2 / 3; chunk = q2 % 3; }
        int row = tile * 32 + (l & 31);
        int orow = inv_pi(row);
        int kb = (j >> 1) * 8 + 4 * gq + (j & 1) * 2;
        float v[2] = {0.f, 0.f};
        if (orow >= 0) {
#pragma unroll
            for (int s = 0; s < 2; ++s) {
                int k = kb + s;
                float val = 0.f;
                if (fid < 8) {
                    bool bwd = fid >= 4;
                    if (chunk == 0) {
                        if (k < 6)       val = (bwd ? wih0r : wih0)[orow * 6 + k];
                        else if (k == 6) val = (bwd ? bih0r[orow] + bhh0r[orow]
                                                    : bih0[orow] + bhh0[orow]);
                    } else { if (k < 10) val = (bwd ? whh0r : whh0)[orow * 10 + k]; }
                } else {
                    if (chunk == 0)      { if (k < 10) val = wih1r[orow * 20 + k]; }
                    else if (chunk == 1) { if (k < 10) val = wih1r[orow * 20 + 10 + k]; }
                    else {
                        if (k < 10)       val = whh1r[orow * 10 + k];
                        else if (k == 10) val = bih1r[orow] + bhh1r[orow];
                    }
                }
                v[s] = val;
            }
        }
        ws[WS_OLD + (fid * 64 + l) * 4 + j] = pk_h16(v[0], v[1]);
    }
}
struct LdsFB { u32 x[TT][3][32]; float m[TT][32]; u32 hf[TT][160]; };
__global__ __launch_bounds__(64)
void bilstm_fb(
    const int*   __restrict__ eidx, const float* __restrict__ f,
    const float* __restrict__ emb,  const float* __restrict__ fw,
    const float* __restrict__ fb,
    const u32* __restrict__ wsr, float* __restrict__ out)
{
    __shared__ LdsFB lds;
    const int  lane = threadIdx.x;
    const int  e    = lane & 31;
    const bool hi   = lane >= 32;
    const int  wid  = blockIdx.x;
    const int  b0   = wid * 32;
    const int  xaddr = (lane ^ 32) << 2;
    {
        float fw0=fw[0],fw1=fw[1],fw2=fw[2],fw3=fw[3],fw4=fw[4];
        float fw5=fw[5],fw6=fw[6],fw7=fw[7],fw8=fw[8];
        float fb0=fb[0],fb1=fb[1],fb2=fb[2];
#pragma unroll 1
        for (int it = 0; it < 10; ++it) {
            int idx = lane + it * 64;
            int ee = idx / 20, t = idx - ee * 20;
            int gi = (b0 + ee) * TT + t;
            float f0 = f[gi * 3], f1 = f[gi * 3 + 1], f2v = f[gi * 3 + 2];
            int ei = eidx[gi] * 3;
            float x0 = emb[ei], x1 = emb[ei + 1], x2 = emb[ei + 2];
            float x3 = fmaf(fw0, f0, fmaf(fw1, f1, fmaf(fw2, f2v, fb0)));
            float x4 = fmaf(fw3, f0, fmaf(fw4, f1, fmaf(fw5, f2v, fb1)));
            float x5 = fmaf(fw6, f0, fmaf(fw7, f1, fmaf(fw8, f2v, fb2)));
            lds.x[t][0][ee] = pk_h16(x0, x1);
            lds.x[t][1][ee] = pk_h16(x2, x3);
            lds.x[t][2][ee] = pk_h16(x4, x5);
            lds.m[t][ee]    = (f1 != 0.f) ? 1.f : 0.f;
        }
    }
    const u32x4* wv = (const u32x4*)(wsr + WS_OLD);
    const f32x16 zf = {};
    {
        u32x4 wf0 = wv[0 * 64 + lane], wf1 = wv[1 * 64 + lane];
        u32x4 wf2 = wv[2 * 64 + lane], wf3 = wv[3 * 64 + lane];
        float cf[5] = {0,0,0,0,0}, hv[5] = {0,0,0,0,0};
        u32x4 bx0;
        {
            u32 x01 = lds.x[0][0][e], x23 = lds.x[0][1][e], x45 = lds.x[0][2][e];
            bx0[0] = hi ? x45 : x01; bx0[1] = hi ? PKB : x23; bx0[2] = 0u; bx0[3] = 0u;
        }
        f32x16 a0x = MFMA32(wf0, bx0, zf);
        f32x16 a1x = MFMA32(wf2, bx0, zf);
        u32x4 bh;
#pragma unroll 1
        for (int t = 0; t < TT; ++t) {
            f32x16 a0 = a0x, a1 = a1x;
            if (t > 0) { a0 = MFMA32(wf1, bh, a0); a1 = MFMA32(wf3, bh, a1); }
            if (t + 1 < TT) {
                u32 x01 = lds.x[t+1][0][e], x23 = lds.x[t+1][1][e], x45 = lds.x[t+1][2][e];
                u32x4 bx; bx[0] = hi ? x45 : x01; bx[1] = hi ? PKB : x23; bx[2] = 0u; bx[3] = 0u;
                a0x = MFMA32(wf0, bx, zf);
                a1x = MFMA32(wf2, bx, zf);
            }
            cell_update5(a0, a1, cf, hv);
            bh = pack_h32(hv, hi, xaddr, 0u);
            lds.hf[t][lane * 2] = bh[0]; lds.hf[t][lane * 2 + 1] = bh[1];
            if (!hi) lds.hf[t][128 + e] = bh[2];
        }
    }
    {
        u32x4 wb0 = wv[4 * 64 + lane], wb1 = wv[5 * 64 + lane];
        u32x4 wb2 = wv[6 * 64 + lane], wb3 = wv[7 * 64 + lane];
        u32x4 wB0 = wv[8 * 64 + lane], wB1 = wv[9 * 64 + lane], wB2 = wv[10 * 64 + lane];
        u32x4 wB3 = wv[11 * 64 + lane], wB4 = wv[12 * 64 + lane], wB5 = wv[13 * 64 + lane];
        float cb[5] = {0,0,0,0,0}, hbv[5] = {0,0,0,0,0};
        float cc[5] = {0,0,0,0,0}, h1v[5] = {0,0,0,0,0};
        float tot = 0.f;
        {
            u32 x01 = lds.x[TT-1][0][e], x23 = lds.x[TT-1][1][e], x45 = lds.x[TT-1][2][e];
            u32x4 bx; bx[0] = hi ? x45 : x01; bx[1] = hi ? PKB : x23; bx[2] = 0u; bx[3] = 0u;
            f32x16 a0 = MFMA32(wb0, bx, zf);
            f32x16 a1 = MFMA32(wb2, bx, zf);
            cell_update5(a0, a1, cb, hbv);
        }
        uint2 cur2 = make_uint2(lds.hf[TT-1][lane * 2], lds.hf[TT-1][lane * 2 + 1]);
        u32   curw = lds.hf[TT-1][128 + e];
#pragma unroll 1
        for (int t = TT - 1; t >= 1; --t) {
            uint2 nxt2 = make_uint2(lds.hf[t-1][lane * 2], lds.hf[t-1][lane * 2 + 1]);
            u32   nxtw = lds.hf[t-1][128 + e];
            u32x4 shared = pack_h32(hbv, hi, xaddr, 0u);
            u32x4 bh1    = pack_h32(h1v, hi, xaddr, hi ? 0u : PKB);
            u32x4 bhf; bhf[0] = cur2.x; bhf[1] = cur2.y; bhf[2] = hi ? 0u : curw; bhf[3] = 0u;
            f32x16 B0 = MFMA32(wB0, bhf, zf); B0 = MFMA32(wB1, shared, B0); B0 = MFMA32(wB2, bh1, B0);
            f32x16 B1 = MFMA32(wB3, bhf, zf); B1 = MFMA32(wB4, shared, B1); B1 = MFMA32(wB5, bh1, B1);
            u32 x01 = lds.x[t-1][0][e], x23 = lds.x[t-1][1][e], x45 = lds.x[t-1][2][e];
            u32x4 bx; bx[0] = hi ? x45 : x01; bx[1] = hi ? PKB : x23; bx[2] = 0u; bx[3] = 0u;
            f32x16 A0 = MFMA32(wb0, bx, zf); A0 = MFMA32(wb1, shared, A0);
            f32x16 A1 = MFMA32(wb2, bx, zf); A1 = MFMA32(wb3, shared, A1);
            cell_update5(B0, B1, cc, h1v);
            if (hi) {
                float ip = fmaxf(h1v[4] * lds.m[t][e], 0.f);
                out[BB + (b0 + e) * TT + t] = ip;
                tot += ip;
            }
            cell_update5(A0, A1, cb, hbv);
            cur2 = nxt2; curw = nxtw;
        }
        {
            u32x4 shared = pack_h32(hbv, hi, xaddr, 0u);
            u32x4 bh1    = pack_h32(h1v, hi, xaddr, hi ? 0u : PKB);
            u32x4 bhf; bhf[0] = cur2.x; bhf[1] = cur2.y; bhf[2] = hi ? 0u : curw; bhf[3] = 0u;
            f32x16 B0 = MFMA32(wB0, bhf, zf); B0 = MFMA32(wB1, shared, B0); B0 = MFMA32(wB2, bh1, B0);
            f32x16 B1 = MFMA32(wB3, bhf, zf); B1 = MFMA32(wB4, shared, B1); B1 = MFMA32(wB5, bh1, B1);
            cell_update5(B0, B1, cc, h1v);
            if (hi) {
                float ip = fmaxf(h1v[4] * lds.m[0][e], 0.f);
                out[BB + (b0 + e) * TT + 0] = ip;
                tot += ip;
                out[b0 + e] = tot;
            }
        }
    }
}

extern "C" void kernel_launch(void* const* d_in, const int* in_sizes, int n_in,
                              void* d_out, int out_size, void* d_ws, size_t ws_size,
                              hipStream_t stream) {
    const int*   eidx  = (const int*)  d_in[0];
    const float* f     = (const float*)d_in[1];
    const float* emb   = (const float*)d_in[2];
    const float* fw    = (const float*)d_in[3];
    const float* fb    = (const float*)d_in[4];
    const float* wih0  = (const float*)d_in[5];
    const float* whh0  = (const float*)d_in[6];
    const float* bih0  = (const float*)d_in[7];
    const float* bhh0  = (const float*)d_in[8];
    const float* wih0r = (const float*)d_in[9];
    const float* whh0r = (const float*)d_in[10];
    const float* bih0r = (const float*)d_in[11];
    const float* bhh0r = (const float*)d_in[12];
    // d_in[13..16] = layer-1 forward weights: dead (output uses only bwd unit 9)
    const float* wih1r = (const float*)d_in[17];
    const float* whh1r = (const float*)d_in[18];
    const float* bih1r = (const float*)d_in[19];
    const float* bhh1r = (const float*)d_in[20];
    float* out = (float*)d_out;
    u32* ws = (u32*)d_ws;

    const size_t need16 = (size_t)(WS_FR + (size_t)NG16 * TT * FR_ROW + 64) * 4;
    if (ws_size >= need16) {
        hipLaunchKernelGGL(prep16, dim3(1), dim3(256), 0, stream,
                           wih0, whh0, bih0, bhh0, wih0r, whh0r, bih0r, bhh0r,
                           wih1r, whh1r, bih1r, bhh1r, ws);
        hipLaunchKernelGGL(bilstm8, dim3(NG16 / 2), dim3(256), 0, stream,
                           eidx, f, emb, fw, fb, ws, ws + WS_FR, out);
    } else {
        hipLaunchKernelGGL(prep_old, dim3(1), dim3(256), 0, stream,
                           wih0, whh0, bih0, bhh0, wih0r, whh0r, bih0r, bhh0r,
                           wih1r, whh1r, bih1r, bhh1r, ws);
        hipLaunchKernelGGL(bilstm_fb, dim3(BB / 32), dim3(64), 0, stream,
                           eidx, f, emb, fw, fb, ws, out);
    }
}